// Round 1
// baseline (3015.173 us; speedup 1.0000x reference)
//
#include <hip/hip_runtime.h>
#include <hip/hip_bf16.h>

#define B_DIM 32
#define T_DIM 8192
#define C_DIM 32
#define N_ELEM (B_DIM * T_DIM * C_DIM)      /* 8388608 */
#define SUM_PT 16383
#define BITS_ELEM (B_DIM * SUM_PT * C_DIM)  /* 16776192 */
#define NLEVEL 14
#define QSCALE 0.17677669529663687f         /* 1/sqrt(32) */
#define ALPHA  70.710678118654755f          /* 4*INV_TEMP/sqrt(32) */

__device__ __forceinline__ float entf(float x) { return -(x * logf(x + 1e-8f)); }

// ---------------------------------------------------------------------------
// Area-downsample: dst[b,j,c] = mean over window W=T/pt of src[b, jW..jW+W, c]
// Block = 256 threads covering 64 consecutive t for one b.
// W >= 64: register reduce -> one atomicAdd per c (dst must be pre-zeroed).
// W <  64: LDS tile, direct writes (windows are contained in the 64-t block).
// ---------------------------------------------------------------------------
__global__ void pool_kernel(const float* __restrict__ src, float* __restrict__ dst, int pt) {
    const int W = T_DIM / pt;
    const int blocksPerB = T_DIM / 64;              // 128
    const int b = blockIdx.x / blocksPerB;
    const int t0 = (blockIdx.x % blocksPerB) * 64;
    const int c = threadIdx.x & 31;
    const int row = threadIdx.x >> 5;               // 0..7
    const float* s = src + ((size_t)b * T_DIM + t0) * C_DIM;

    if (W >= 64) {
        float acc = 0.f;
#pragma unroll
        for (int i = 0; i < 8; ++i) acc += s[(i * 8 + row) * C_DIM + c];
        __shared__ float red[8][32];
        red[row][c] = acc;
        __syncthreads();
        if (row == 0) {
            float s0 = red[0][c] + red[1][c] + red[2][c] + red[3][c]
                     + red[4][c] + red[5][c] + red[6][c] + red[7][c];
            atomicAdd(&dst[((size_t)b * pt + (t0 / W)) * C_DIM + c], s0 * (1.0f / (float)W));
        }
    } else {
        __shared__ float tile[64 * 32];
#pragma unroll
        for (int i = 0; i < 8; ++i) tile[threadIdx.x + i * 256] = s[threadIdx.x + i * 256];
        __syncthreads();
        const int nOut = 64 / W;                    // 2..32
        const int total = nOut * 32;
        for (int o = threadIdx.x; o < total; o += 256) {
            const int jl = o >> 5;
            const int cc = o & 31;
            float sum = 0.f;
            for (int i = 0; i < W; ++i) sum += tile[(jl * W + i) * 32 + cc];
            dst[((size_t)b * pt + (t0 / W) + jl) * C_DIM + cc] = sum * (1.0f / (float)W);
        }
    }
}

// ---------------------------------------------------------------------------
// BSQ on pooled buffer P (B, pt, C): overwrite P with quant (=zhat), write
// bits (as 0.0/1.0 float), accumulate loss partials into acc[level*64 + ...]
// acc layout per level: [0]=sum ent, [1]=sum commit, [2..33]=per-channel sum p
// One 32-lane group per position.
// ---------------------------------------------------------------------------
__global__ void bsq_kernel(float* __restrict__ P, float* __restrict__ outBits,
                           float* __restrict__ acc, int pt, int level) {
    const int pos = blockIdx.x * 8 + (threadIdx.x >> 5);
    const int c = threadIdx.x & 31;
    const int npos = B_DIM * pt;
    const bool act = pos < npos;

    float v = 0.f;
    if (act) v = P[(size_t)pos * C_DIM + c];
    float sq = v * v;
#pragma unroll
    for (int m = 16; m >= 1; m >>= 1) sq += __shfl_xor(sq, m, 32);
    const float norm = sqrtf(sq);
    const float z = v / fmaxf(norm, 1e-12f);
    const float zhat = (z > 0.f) ? QSCALE : -QSCALE;

    float p = 0.f, e = 0.f, commit = 0.f;
    if (act) {
        P[(size_t)pos * C_DIM + c] = zhat;
        const int b = pos / pt;
        const int j = pos - b * pt;
        outBits[((size_t)b * SUM_PT + (pt - 1) + j) * C_DIM + c] = (z > 0.f) ? 1.0f : 0.0f;
        const float d = zhat - z;
        commit = d * d;
        const float a = ALPHA * z;                  // p = sigmoid(-a)
        p = 1.0f / (1.0f + expf(a));
        e = entf(p) + entf(1.0f - p);
    }

    // block reductions
    __shared__ float sP[256];
    __shared__ float sEC[16];
    float eg = e, cg = commit;
#pragma unroll
    for (int m = 16; m >= 1; m >>= 1) { eg += __shfl_xor(eg, m, 32); cg += __shfl_xor(cg, m, 32); }
    if (c == 0) { sEC[(threadIdx.x >> 5) * 2] = eg; sEC[(threadIdx.x >> 5) * 2 + 1] = cg; }
    sP[threadIdx.x] = p;
    __syncthreads();
    if (threadIdx.x < 32) {
        float ps = 0.f;
#pragma unroll
        for (int r = 0; r < 8; ++r) ps += sP[threadIdx.x + r * 32];
        atomicAdd(&acc[level * 64 + 2 + threadIdx.x], ps);
    }
    if (threadIdx.x == 0) {
        float se = 0.f, sc = 0.f;
#pragma unroll
        for (int g = 0; g < 8; ++g) { se += sEC[2 * g]; sc += sEC[2 * g + 1]; }
        atomicAdd(&acc[level * 64 + 0], se);
        atomicAdd(&acc[level * 64 + 1], sc);
    }
}

// ---------------------------------------------------------------------------
// R_new = src - linear_up(Q, pt -> T).  src is f for level 0, else R (in-place).
// ---------------------------------------------------------------------------
__global__ void update_kernel(const float* __restrict__ src, float* __restrict__ dst,
                              const float* __restrict__ Q, int pt) {
    const size_t idx = (size_t)blockIdx.x * 256 + threadIdx.x;   // grid exactly N/256
    const int c = (int)(idx & 31);
    const int t = (int)((idx >> 5) & (T_DIM - 1));
    const int b = (int)(idx >> 18);
    const float scale = (float)pt * (1.0f / (float)T_DIM);
    float pos = ((float)t + 0.5f) * scale - 0.5f;
    pos = fminf(fmaxf(pos, 0.f), (float)(pt - 1));
    const int lo = (int)pos;
    const int hi = min(lo + 1, pt - 1);
    const float w = pos - (float)lo;
    const float* Qb = Q + (size_t)b * pt * C_DIM;
    const float val = Qb[lo * C_DIM + c] * (1.0f - w) + Qb[hi * C_DIM + c] * w;
    dst[idx] = src[idx] - val;
}

// ---------------------------------------------------------------------------
// Level 13 (pt == T): BSQ on R directly + out = f - R + zhat, bits, losses.
// ---------------------------------------------------------------------------
__global__ void final_kernel(const float* __restrict__ f, const float* __restrict__ R,
                             float* __restrict__ outQ, float* __restrict__ outBits,
                             float* __restrict__ acc) {
    const int pos = blockIdx.x * 8 + (threadIdx.x >> 5);   // 0 .. B*T-1
    const int c = threadIdx.x & 31;
    const size_t idx = (size_t)pos * C_DIM + c;
    const float v = R[idx];
    float sq = v * v;
#pragma unroll
    for (int m = 16; m >= 1; m >>= 1) sq += __shfl_xor(sq, m, 32);
    const float norm = sqrtf(sq);
    const float z = v / fmaxf(norm, 1e-12f);
    const float zhat = (z > 0.f) ? QSCALE : -QSCALE;

    const int b = pos >> 13;
    const int t = pos & (T_DIM - 1);
    outBits[((size_t)b * SUM_PT + (T_DIM - 1) + t) * C_DIM + c] = (z > 0.f) ? 1.0f : 0.0f;
    outQ[idx] = f[idx] - v + zhat;

    const float d = zhat - z;
    const float commit = d * d;
    const float a = ALPHA * z;
    const float p = 1.0f / (1.0f + expf(a));
    const float e = entf(p) + entf(1.0f - p);

    __shared__ float sP[256];
    __shared__ float sEC[16];
    float eg = e, cg = commit;
#pragma unroll
    for (int m = 16; m >= 1; m >>= 1) { eg += __shfl_xor(eg, m, 32); cg += __shfl_xor(cg, m, 32); }
    if (c == 0) { sEC[(threadIdx.x >> 5) * 2] = eg; sEC[(threadIdx.x >> 5) * 2 + 1] = cg; }
    sP[threadIdx.x] = p;
    __syncthreads();
    if (threadIdx.x < 32) {
        float ps = 0.f;
#pragma unroll
        for (int r = 0; r < 8; ++r) ps += sP[threadIdx.x + r * 32];
        atomicAdd(&acc[13 * 64 + 2 + threadIdx.x], ps);
    }
    if (threadIdx.x == 0) {
        float se = 0.f, sc = 0.f;
#pragma unroll
        for (int g = 0; g < 8; ++g) { se += sEC[2 * g]; sc += sEC[2 * g + 1]; }
        atomicAdd(&acc[13 * 64 + 0], se);
        atomicAdd(&acc[13 * 64 + 1], sc);
    }
}

// ---------------------------------------------------------------------------
// aux[k] = ((ent_sum/cnt) - cb_ent)/INV_TEMP * ENTROPY_W + (commit_sum/cnt)*COMMIT_W
// ---------------------------------------------------------------------------
__global__ void finalize_kernel(const float* __restrict__ acc, float* __restrict__ outL) {
    const int k = threadIdx.x >> 5;
    const int c = threadIdx.x & 31;
    if (k >= NLEVEL) return;
    const float cnt = (float)(B_DIM << k);       // B * pt_k
    const float avg_p = acc[k * 64 + 2 + c] / cnt;
    float ec = entf(avg_p) + entf(1.0f - avg_p);
#pragma unroll
    for (int m = 16; m >= 1; m >>= 1) ec += __shfl_xor(ec, m, 32);
    if (c == 0) {
        const float per_sample = acc[k * 64 + 0] / cnt;
        const float commit = acc[k * 64 + 1] / cnt;
        const float pen = (per_sample - ec) * (1.0f / 100.0f);
        outL[k] = pen * 0.1f + commit * 0.2f;
    }
}

extern "C" void kernel_launch(void* const* d_in, const int* in_sizes, int n_in,
                              void* d_out, int out_size, void* d_ws, size_t ws_size,
                              hipStream_t stream) {
    (void)in_sizes; (void)n_in; (void)out_size; (void)ws_size;
    const float* f = (const float*)d_in[0];
    float* outQ = (float*)d_out;                       // N_ELEM floats; also used as R scratch
    float* outBits = outQ + N_ELEM;                    // BITS_ELEM floats
    float* outL = outBits + BITS_ELEM;                 // 14 floats
    float* R = outQ;                                   // residual lives in outQ region
    float* P = (float*)d_ws;                           // pooled/quant: up to B*4096*C floats
    float* acc = P + (size_t)B_DIM * 4096 * C_DIM;     // 14*64 floats

    hipMemsetAsync(acc, 0, NLEVEL * 64 * sizeof(float), stream);

    for (int k = 0; k < 13; ++k) {
        const int pt = 1 << k;
        const int W = T_DIM / pt;
        const float* src = (k == 0) ? f : R;
        if (W >= 64)
            hipMemsetAsync(P, 0, (size_t)B_DIM * pt * C_DIM * sizeof(float), stream);
        pool_kernel<<<B_DIM * (T_DIM / 64), 256, 0, stream>>>(src, P, pt);
        bsq_kernel<<<(B_DIM * pt + 7) / 8, 256, 0, stream>>>(P, outBits, acc, pt, k);
        update_kernel<<<N_ELEM / 256, 256, 0, stream>>>(src, R, P, pt);
    }
    final_kernel<<<(B_DIM * T_DIM) / 8, 256, 0, stream>>>(f, R, outQ, outBits, acc);
    finalize_kernel<<<1, 512, 0, stream>>>(acc, outL);
}

// Round 2
// 351.000 us; speedup vs baseline: 8.5902x; 8.5902x over previous
//
#include <hip/hip_runtime.h>
#include <hip/hip_bf16.h>

#define B_DIM 32
#define T_DIM 8192
#define C_DIM 32
#define N_ELEM (B_DIM * T_DIM * C_DIM)      /* 8388608 */
#define SUM_PT 16383
#define BITS_ELEM (B_DIM * SUM_PT * C_DIM)  /* 16776192 */
#define NLEVEL 14
#define PARTW 4096                          /* partial-sum columns (max grid) */
#define QSCALE 0.17677669529663687f         /* 1/sqrt(32) */
#define ALPHA  70.710678118654755f          /* 4*INV_TEMP/sqrt(32) */

__device__ __forceinline__ float entf(float x) { return -(x * logf(x + 1e-8f)); }

// Per-block partial write: partial[level][comp][col], comp: 0=ent,1=commit,2..33=p[c]
__device__ __forceinline__ void write_partials(float eAcc, float cAcc, float pAcc,
                                               float* __restrict__ partial, int level, int col) {
    __shared__ float sP[256];
    __shared__ float sEC[16];
    const int grp = threadIdx.x >> 5, c = threadIdx.x & 31;
    float eg = eAcc, cg = cAcc;
#pragma unroll
    for (int m = 16; m >= 1; m >>= 1) { eg += __shfl_xor(eg, m, 32); cg += __shfl_xor(cg, m, 32); }
    if (c == 0) { sEC[grp * 2] = eg; sEC[grp * 2 + 1] = cg; }
    sP[threadIdx.x] = pAcc;
    __syncthreads();
    float* base = partial + (size_t)level * 34 * PARTW;
    if (threadIdx.x < 32) {
        float ps = 0.f;
#pragma unroll
        for (int r = 0; r < 8; ++r) ps += sP[threadIdx.x + r * 32];
        base[(size_t)(2 + threadIdx.x) * PARTW + col] = ps;
    }
    if (threadIdx.x == 0) {
        float se = 0.f, sc = 0.f;
#pragma unroll
        for (int g = 0; g < 8; ++g) { se += sEC[2 * g]; sc += sEC[2 * g + 1]; }
        base[0 * PARTW + col] = se;
        base[(size_t)1 * PARTW + col] = sc;
    }
}

// BSQ core on a pooled vector v (one 32-lane group per position).
// Returns z sign handled by caller; accumulates loss terms.
__device__ __forceinline__ void bsq_point(float v, float* __restrict__ bitsDst,
                                          float& pAcc, float& eAcc, float& cAcc) {
    float sq = v * v;
#pragma unroll
    for (int m = 16; m >= 1; m >>= 1) sq += __shfl_xor(sq, m, 32);
    const float z = v / fmaxf(sqrtf(sq), 1e-12f);
    const float zhat = (z > 0.f) ? QSCALE : -QSCALE;
    *bitsDst = (z > 0.f) ? 1.0f : 0.0f;
    const float d = zhat - z;
    cAcc += d * d;
    const float p = 1.0f / (1.0f + expf(ALPHA * z));
    pAcc += p;
    eAcc += entf(p) + entf(1.0f - p);
}

// ---------------------------------------------------------------------------
// Levels 0..6 stage A: pool 64 consecutive t -> one mean, into P2[B,128,C].
// ---------------------------------------------------------------------------
__global__ void poolA_kernel(const float* __restrict__ src, float* __restrict__ P2) {
    const int b = blockIdx.x >> 7;
    const int t0 = (blockIdx.x & 127) << 6;
    const int c = threadIdx.x & 31;
    const int row = threadIdx.x >> 5;
    const float* s = src + ((size_t)b * T_DIM + t0) * C_DIM;
    float acc = 0.f;
#pragma unroll
    for (int i = 0; i < 8; ++i) acc += s[(i * 8 + row) * C_DIM + c];
    __shared__ float red[8][32];
    red[row][c] = acc;
    __syncthreads();
    if (row == 0) {
        float s0 = red[0][c] + red[1][c] + red[2][c] + red[3][c]
                 + red[4][c] + red[5][c] + red[6][c] + red[7][c];
        P2[((size_t)b * 128 + (t0 >> 6)) * C_DIM + c] = s0 * (1.0f / 64.0f);
    }
}

// ---------------------------------------------------------------------------
// Levels 0..6 stage B: pool P2[B,128,C] by W2=128>>level + BSQ fused.
// One block per b (32 blocks).
// ---------------------------------------------------------------------------
__global__ void bsq_small_kernel(const float* __restrict__ P2, float* __restrict__ outBits,
                                 float* __restrict__ partial, int level) {
    const int pt = 1 << level;          // 1..64
    const int W2 = 128 >> level;        // 128..2
    const int b = blockIdx.x;
    __shared__ float tile[128 * 32];
    for (int i = threadIdx.x; i < 128 * 32; i += 256) tile[i] = P2[(size_t)b * 128 * 32 + i];
    __syncthreads();
    const int grp = threadIdx.x >> 5, c = threadIdx.x & 31;
    float pAcc = 0.f, eAcc = 0.f, cAcc = 0.f;
    for (int o = grp; o < pt; o += 8) {
        float v = 0.f;
        for (int i = 0; i < W2; ++i) v += tile[(o * W2 + i) * 32 + c];
        v *= (1.0f / (float)W2);
        bsq_point(v, &outBits[((size_t)b * SUM_PT + (pt - 1) + o) * C_DIM + c], pAcc, eAcc, cAcc);
    }
    write_partials(eAcc, cAcc, pAcc, partial, level, b);
}

// ---------------------------------------------------------------------------
// Levels 7..12: fused pool (window W=T>>level <= 64, block-local) + BSQ.
// Grid = B * 128 blocks of 256.
// ---------------------------------------------------------------------------
__global__ void pool_bsq_kernel(const float* __restrict__ src, float* __restrict__ outBits,
                                float* __restrict__ partial, int level) {
    const int pt = 1 << level;
    const int W = T_DIM >> level;       // 64..2
    const int nOut = 64 / W;            // 1..32
    const int b = blockIdx.x >> 7;
    const int t0 = (blockIdx.x & 127) << 6;
    __shared__ float tile[64 * 32];
    const float* s = src + ((size_t)b * T_DIM + t0) * C_DIM;
#pragma unroll
    for (int i = 0; i < 8; ++i) tile[threadIdx.x + i * 256] = s[threadIdx.x + i * 256];
    __syncthreads();
    const int grp = threadIdx.x >> 5, c = threadIdx.x & 31;
    float pAcc = 0.f, eAcc = 0.f, cAcc = 0.f;
    const int j0 = t0 / W;
    for (int o = grp; o < nOut; o += 8) {
        float v = 0.f;
        for (int i = 0; i < W; ++i) v += tile[(o * W + i) * 32 + c];
        v *= (1.0f / (float)W);
        bsq_point(v, &outBits[((size_t)b * SUM_PT + (pt - 1) + j0 + o) * C_DIM + c], pAcc, eAcc, cAcc);
    }
    write_partials(eAcc, cAcc, pAcc, partial, level, blockIdx.x);
}

// ---------------------------------------------------------------------------
// R_new = src - linear_up(quant, pt -> T); quant derived from bits: (2b-1)*QSCALE.
// float4 over channels. Grid = N_ELEM/1024 blocks of 256.
// ---------------------------------------------------------------------------
__global__ void update_kernel(const float* __restrict__ src, float* __restrict__ dst,
                              const float* __restrict__ bits, int pt) {
    const size_t q = (size_t)blockIdx.x * 256 + threadIdx.x;
    const size_t idx = q * 4;
    const int c = (int)(idx & 31);
    const int t = (int)((idx >> 5) & (T_DIM - 1));
    const int b = (int)(idx >> 18);
    const float scale = (float)pt * (1.0f / (float)T_DIM);
    float pos = ((float)t + 0.5f) * scale - 0.5f;
    pos = fminf(fmaxf(pos, 0.f), (float)(pt - 1));
    const int lo = (int)pos;
    const int hi = min(lo + 1, pt - 1);
    const float w = pos - (float)lo;
    const float* Bb = bits + ((size_t)b * SUM_PT + (pt - 1)) * C_DIM + c;
    const float4 blo = *(const float4*)(Bb + (size_t)lo * C_DIM);
    const float4 bhi = *(const float4*)(Bb + (size_t)hi * C_DIM);
    const float4 s = *(const float4*)(src + idx);
    float4 r;
    const float iw = 1.0f - w;
    r.x = s.x - fmaf(blo.x * iw + bhi.x * w, 2.0f * QSCALE, -QSCALE);
    r.y = s.y - fmaf(blo.y * iw + bhi.y * w, 2.0f * QSCALE, -QSCALE);
    r.z = s.z - fmaf(blo.z * iw + bhi.z * w, 2.0f * QSCALE, -QSCALE);
    r.w = s.w - fmaf(blo.w * iw + bhi.w * w, 2.0f * QSCALE, -QSCALE);
    *(float4*)(dst + idx) = r;
}

// ---------------------------------------------------------------------------
// Level 13 (pt == T): BSQ on R + out = f - R + zhat, bits, loss partials.
// Grid-stride, 4096 blocks of 256.
// ---------------------------------------------------------------------------
__global__ void final_kernel(const float* __restrict__ f, const float* __restrict__ R,
                             float* __restrict__ outQ, float* __restrict__ outBits,
                             float* __restrict__ partial) {
    const int grp = threadIdx.x >> 5, c = threadIdx.x & 31;
    const int npos = B_DIM * T_DIM;
    float pAcc = 0.f, eAcc = 0.f, cAcc = 0.f;
    for (int pos = blockIdx.x * 8 + grp; pos < npos; pos += gridDim.x * 8) {
        const size_t idx = (size_t)pos * C_DIM + c;
        const float v = R[idx];
        float sq = v * v;
#pragma unroll
        for (int m = 16; m >= 1; m >>= 1) sq += __shfl_xor(sq, m, 32);
        const float z = v / fmaxf(sqrtf(sq), 1e-12f);
        const float zhat = (z > 0.f) ? QSCALE : -QSCALE;
        const int b = pos >> 13;
        const int t = pos & (T_DIM - 1);
        outBits[((size_t)b * SUM_PT + (T_DIM - 1) + t) * C_DIM + c] = (z > 0.f) ? 1.0f : 0.0f;
        outQ[idx] = f[idx] - v + zhat;
        const float d = zhat - z;
        cAcc += d * d;
        const float p = 1.0f / (1.0f + expf(ALPHA * z));
        pAcc += p;
        eAcc += entf(p) + entf(1.0f - p);
    }
    write_partials(eAcc, cAcc, pAcc, partial, 13, blockIdx.x);
}

// ---------------------------------------------------------------------------
// Sum partials: one wave per (level, comp). acc[level*64+comp] = sum.
// ---------------------------------------------------------------------------
__global__ void reduce_partials(const float* __restrict__ partial, float* __restrict__ acc) {
    const int level = blockIdx.x / 34;
    const int comp = blockIdx.x % 34;
    const int nblk = (level < 7) ? 32 : PARTW;
    const float* s = partial + ((size_t)level * 34 + comp) * PARTW;
    float v = 0.f;
    for (int i = threadIdx.x; i < nblk; i += 64) v += s[i];
#pragma unroll
    for (int m = 32; m >= 1; m >>= 1) v += __shfl_xor(v, m, 64);
    if (threadIdx.x == 0) acc[level * 64 + comp] = v;
}

// ---------------------------------------------------------------------------
// aux[k] = ((ent/cnt) - cb_ent)/INV_TEMP * ENTROPY_W + (commit/cnt)*COMMIT_W
// ---------------------------------------------------------------------------
__global__ void finalize_kernel(const float* __restrict__ acc, float* __restrict__ outL) {
    const int k = threadIdx.x >> 5;
    const int c = threadIdx.x & 31;
    if (k >= NLEVEL) return;
    const float cnt = (float)(B_DIM << k);
    const float avg_p = acc[k * 64 + 2 + c] / cnt;
    float ec = entf(avg_p) + entf(1.0f - avg_p);
#pragma unroll
    for (int m = 16; m >= 1; m >>= 1) ec += __shfl_xor(ec, m, 32);
    if (c == 0) {
        const float per_sample = acc[k * 64 + 0] / cnt;
        const float commit = acc[k * 64 + 1] / cnt;
        const float pen = (per_sample - ec) * (1.0f / 100.0f);
        outL[k] = pen * 0.1f + commit * 0.2f;
    }
}

extern "C" void kernel_launch(void* const* d_in, const int* in_sizes, int n_in,
                              void* d_out, int out_size, void* d_ws, size_t ws_size,
                              hipStream_t stream) {
    (void)in_sizes; (void)n_in; (void)out_size; (void)ws_size;
    const float* f = (const float*)d_in[0];
    float* outQ = (float*)d_out;                       // N_ELEM; doubles as residual R
    float* outBits = outQ + N_ELEM;                    // BITS_ELEM (bits as 0.0/1.0)
    float* outL = outBits + BITS_ELEM;                 // 14 floats
    float* R = outQ;

    float* partial = (float*)d_ws;                     // NLEVEL*34*PARTW floats (~7.8MB)
    float* acc = partial + (size_t)NLEVEL * 34 * PARTW;// NLEVEL*64 floats
    float* P2 = acc + NLEVEL * 64;                     // B*128*C floats (0.5MB)

    for (int k = 0; k < 7; ++k) {
        const float* src = (k == 0) ? f : R;
        poolA_kernel<<<B_DIM * 128, 256, 0, stream>>>(src, P2);
        bsq_small_kernel<<<B_DIM, 256, 0, stream>>>(P2, outBits, partial, k);
        update_kernel<<<N_ELEM / 1024, 256, 0, stream>>>(src, R, outBits, 1 << k);
    }
    for (int k = 7; k < 13; ++k) {
        pool_bsq_kernel<<<B_DIM * 128, 256, 0, stream>>>(R, outBits, partial, k);
        update_kernel<<<N_ELEM / 1024, 256, 0, stream>>>(R, R, outBits, 1 << k);
    }
    final_kernel<<<4096, 256, 0, stream>>>(f, R, outQ, outBits, partial);
    reduce_partials<<<NLEVEL * 34, 64, 0, stream>>>(partial, acc);
    finalize_kernel<<<1, 512, 0, stream>>>(acc, outL);
}

// Round 4
// 276.509 us; speedup vs baseline: 10.9044x; 1.2694x over previous
//
#include <hip/hip_runtime.h>

#define B_DIM 32
#define T_DIM 8192
#define C_DIM 32
#define N_ELEM (B_DIM * T_DIM * C_DIM)      /* 8388608 */
#define SUM_PT 16383
#define BITS_ELEM (B_DIM * SUM_PT * C_DIM)  /* 16776192 */
#define NLEVEL 14
#define PARTW 2048
#define QSCALE 0.17677669529663687f         /* 1/sqrt(32) */
#define ALPHA  70.710678118654755f          /* 4*INV_TEMP/sqrt(32) */

__device__ __forceinline__ float entf(float x) { return -(x * logf(x + 1e-8f)); }
__device__ __forceinline__ float qval(float bit) { return bit * (2.0f * QSCALE) - QSCALE; }

// linear-interp (align_corners=False) of level-j quant at T-grid position t.
// base = bits row 0 of (b, level j) at channel c; row stride C_DIM. Exact per reference.
__device__ __forceinline__ float interp_q(const float* base, int ptj, int t) {
    const float a = (float)ptj * (1.0f / (float)T_DIM);
    float pos = ((float)t + 0.5f) * a - 0.5f;
    pos = fminf(fmaxf(pos, 0.0f), (float)(ptj - 1));
    const int lo = (int)pos;
    const int hi = min(lo + 1, ptj - 1);
    const float w = pos - (float)lo;
    return qval(base[(size_t)lo * C_DIM]) * (1.0f - w) + qval(base[(size_t)hi * C_DIM]) * w;
}

// pool_4096(up_T(q_j))[row] = mean of 2 interp samples.
__device__ __forceinline__ float delta_row4096(const float* base, int ptj, int r) {
    return 0.5f * (interp_q(base, ptj, 2 * r) + interp_q(base, ptj, 2 * r + 1));
}

// Closed-form sum over t in [m*64,(m+1)*64) of interp_q (scale-128 pooling window).
// Requires ptj <= 64 (window span < 1 -> at most one floor crossing in the
// unclamped region). All positions are exact dyadics in fp32.
__device__ float pooled_up_sum64(const float* base, int ptj, int m) {
    const int W = 64;
    const float a = (float)ptj * (1.0f / (float)T_DIM);
    const float p0 = ((float)(m * W) + 0.5f) * a - 0.5f;
    const float pmax = (float)(ptj - 1);
    float sum = 0.0f;
    int iL = 0;
    if (p0 < 0.0f) { iL = (int)ceilf(-p0 / a); if (iL > W) iL = W; }
    int iH = W - 1;
    if (p0 + (float)(W - 1) * a > pmax) {
        iH = (int)floorf((pmax - p0) / a);
        if (iH > W - 1) iH = W - 1;
        if (iH < -1) iH = -1;           // whole window above pmax -> 64 clamped taps
    }
    if (iL > 0) sum += (float)iL * qval(base[0]);
    if (iH < W - 1) sum += (float)(W - 1 - iH) * qval(base[(size_t)(ptj - 1) * C_DIM]);
    if (iH >= iL) {
        const float pL = p0 + (float)iL * a;
        int l0 = (int)pL;
        if (l0 > ptj - 1) l0 = ptj - 1;
        const int is = (int)ceilf(((float)(l0 + 1) - p0) / a);
        const int endA = min(is - 1, iH);
        if (endA >= iL) {
            const int nA = endA - iL + 1;
            const float sI = 0.5f * (float)(iL + endA) * (float)nA;
            const float SA = (float)nA * (p0 - (float)l0) + a * sI;
            const float q0 = qval(base[(size_t)l0 * C_DIM]);
            const float q1 = qval(base[(size_t)min(l0 + 1, ptj - 1) * C_DIM]);
            sum += (float)nA * q0 + SA * (q1 - q0);
        }
        const int begB = max(is, iL);
        if (begB <= iH) {
            const int nB = iH - begB + 1;
            const float sI = 0.5f * (float)(begB + iH) * (float)nB;
            const float SB = (float)nB * (p0 - (float)(l0 + 1)) + a * sI;
            const float q1 = qval(base[(size_t)min(l0 + 1, ptj - 1) * C_DIM]);
            const float q2 = qval(base[(size_t)min(l0 + 2, ptj - 1) * C_DIM]);
            sum += (float)nB * q1 + SB * (q2 - q1);
        }
    }
    return sum;
}

// Per-block partial write: partial[level][comp][col], comp: 0=ent,1=commit,2..33=p[c]
__device__ __forceinline__ void write_partials(float eAcc, float cAcc, float pAcc,
                                               float* partial, int level, int col) {
    __shared__ float sP[256];
    __shared__ float sEC[16];
    const int grp = threadIdx.x >> 5, c = threadIdx.x & 31;
    float eg = eAcc, cg = cAcc;
#pragma unroll
    for (int m = 16; m >= 1; m >>= 1) { eg += __shfl_xor(eg, m, 32); cg += __shfl_xor(cg, m, 32); }
    if (c == 0) { sEC[grp * 2] = eg; sEC[grp * 2 + 1] = cg; }
    sP[threadIdx.x] = pAcc;
    __syncthreads();
    float* base = partial + (size_t)level * 34 * PARTW;
    if (threadIdx.x < 32) {
        float ps = 0.f;
#pragma unroll
        for (int r = 0; r < 8; ++r) ps += sP[threadIdx.x + r * 32];
        base[(size_t)(2 + threadIdx.x) * PARTW + col] = ps;
    }
    if (threadIdx.x == 0) {
        float se = 0.f, sc = 0.f;
#pragma unroll
        for (int g = 0; g < 8; ++g) { se += sEC[2 * g]; sc += sEC[2 * g + 1]; }
        base[0 * PARTW + col] = se;
        base[(size_t)1 * PARTW + col] = sc;
    }
}

// BSQ sign + loss accumulation for one pooled value (32-lane group = channels).
__device__ __forceinline__ float bsq_eval(float v, float& bit, float& pA, float& eA, float& cA) {
    float sq = v * v;
#pragma unroll
    for (int m = 16; m >= 1; m >>= 1) sq += __shfl_xor(sq, m, 32);
    const float z = v / fmaxf(sqrtf(sq), 1e-12f);
    bit = (z > 0.f) ? 1.0f : 0.0f;
    const float zh = (z > 0.f) ? QSCALE : -QSCALE;
    const float d = zh - z;
    cA += d * d;
    const float p = 1.0f / (1.0f + expf(ALPHA * z));
    pA += p;
    eA += entf(p) + entf(1.0f - p);
    return zh;
}

// ---------------------------------------------------------------------------
// initA: Racc[b,m,c] = 0.5*(f[b,2m,c]+f[b,2m+1,c])  (pool T -> 4096). float4.
// ---------------------------------------------------------------------------
__global__ void initA_kernel(const float* __restrict__ f, float* __restrict__ Racc) {
    const size_t o4 = (size_t)blockIdx.x * 256 + threadIdx.x;   // grid 4096
    const size_t o = o4 * 4;
    const int c = (int)(o & 31);
    const int m = (int)((o >> 5) & 4095);
    const int b = (int)(o >> 17);
    const size_t in = ((size_t)b * T_DIM + 2 * m) * C_DIM + c;
    const float4 r0 = *(const float4*)(f + in);
    const float4 r1 = *(const float4*)(f + in + C_DIM);
    float4 out;
    out.x = 0.5f * (r0.x + r1.x); out.y = 0.5f * (r0.y + r1.y);
    out.z = 0.5f * (r0.z + r1.z); out.w = 0.5f * (r0.w + r1.w);
    *(float4*)(Racc + o) = out;
}

// ---------------------------------------------------------------------------
// initB: F128[b,m,c] = mean of 32 Racc rows (pool 4096 -> 128).
// ---------------------------------------------------------------------------
__global__ void initB_kernel(const float* __restrict__ Racc, float* __restrict__ F128) {
    const int g = blockIdx.x * 8 + (threadIdx.x >> 5);          // grid 512 -> 4096 groups
    const int c = threadIdx.x & 31;
    const int b = g >> 7, m = g & 127;
    const float* s = Racc + ((size_t)b * 4096 + m * 32) * C_DIM + c;
    float acc = 0.f;
#pragma unroll
    for (int r = 0; r < 32; ++r) acc += s[r * C_DIM];
    F128[((size_t)b * 128 + m) * C_DIM + c] = acc * (1.0f / 32.0f);
}

// ---------------------------------------------------------------------------
// Levels 0..7 fused: one block per b. P128 (corrected pooled residual) in LDS;
// after each level subtract closed-form pooled-up of the new quant.
// ---------------------------------------------------------------------------
__global__ void fused_small_kernel(const float* __restrict__ F128, float* __restrict__ bits,
                                   float* __restrict__ partial) {
    const int b = blockIdx.x;
    __shared__ float P[128 * 32];
    __shared__ float qh[127 * 32];          // bits history, levels 0..6
    const int c = threadIdx.x & 31, grp = threadIdx.x >> 5;
    for (int i = threadIdx.x; i < 128 * 32; i += 256) P[i] = F128[(size_t)b * 128 * 32 + i];
    __syncthreads();
    for (int k = 0; k < 8; ++k) {
        const int pt = 1 << k, W2 = 128 >> k;
        float pAcc = 0.f, eAcc = 0.f, cAcc = 0.f;
        for (int o = grp; o < pt; o += 8) {
            float v = 0.f;
            for (int i = 0; i < W2; ++i) v += P[(o * W2 + i) * 32 + c];
            v *= (1.0f / (float)W2);
            float bit;
            bsq_eval(v, bit, pAcc, eAcc, cAcc);
            bits[((size_t)b * SUM_PT + (pt - 1) + o) * C_DIM + c] = bit;
            if (k < 7) qh[((pt - 1) + o) * 32 + c] = bit;
        }
        write_partials(eAcc, cAcc, pAcc, partial, k, b);   // internal syncthreads
        if (k < 7) {
            for (int m = grp; m < 128; m += 8)
                P[m * 32 + c] -= pooled_up_sum64(&qh[(pt - 1) * 32 + c], 1 << k, m) * (1.0f / 64.0f);
            __syncthreads();
        }
    }
}

// ---------------------------------------------------------------------------
// Levels 8..12: apply previous level's correction to Racc rows inline (write
// back), pool F=4096/pt rows, BSQ. Level 8 applies the j=0..7 batch.
// Grid 2048 x 256, grid-stride over positions.
// ---------------------------------------------------------------------------
__global__ void level_kernel(float* __restrict__ Racc, float* __restrict__ bits,
                             float* __restrict__ partial, int level) {
    const int pt = 1 << level;
    const int F = 4096 / pt;                 // 16..1
    const int c = threadIdx.x & 31, grp = threadIdx.x >> 5;
    const int npos = B_DIM * pt;
    float pAcc = 0.f, eAcc = 0.f, cAcc = 0.f;
    for (int pos = blockIdx.x * 8 + grp; pos < npos; pos += gridDim.x * 8) {
        const int b = pos >> level;
        const int m = pos & (pt - 1);
        float sum = 0.f;
        for (int r = 0; r < F; ++r) {
            const int row = m * F + r;
            const size_t ri = ((size_t)b * 4096 + row) * C_DIM + c;
            float val = Racc[ri];
            if (level == 8) {
                for (int j = 0; j < 8; ++j) {
                    const int ptj = 1 << j;
                    val -= delta_row4096(bits + ((size_t)b * SUM_PT + (ptj - 1)) * C_DIM + c, ptj, row);
                }
            } else {
                const int ptj = pt >> 1;
                val -= delta_row4096(bits + ((size_t)b * SUM_PT + (ptj - 1)) * C_DIM + c, ptj, row);
            }
            Racc[ri] = val;
            sum += val;
        }
        const float v = sum * (1.0f / (float)F);
        float bit;
        bsq_eval(v, bit, pAcc, eAcc, cAcc);
        bits[((size_t)b * SUM_PT + (pt - 1) + m) * C_DIM + c] = bit;
    }
    write_partials(eAcc, cAcc, pAcc, partial, level, blockIdx.x);
}

// ---------------------------------------------------------------------------
// Level 13: R13(t) = f - sum_{j<=12} interp_j(t); out = sum + zhat; bits13; losses.
// ---------------------------------------------------------------------------
__global__ void final_kernel(const float* __restrict__ f, float* __restrict__ outQ,
                             float* bits, float* __restrict__ partial) {
    const int c = threadIdx.x & 31, grp = threadIdx.x >> 5;
    const int npos = B_DIM * T_DIM;
    float pAcc = 0.f, eAcc = 0.f, cAcc = 0.f;
    for (int pos = blockIdx.x * 8 + grp; pos < npos; pos += gridDim.x * 8) {
        const int b = pos >> 13;
        const int t = pos & (T_DIM - 1);
        float up = 0.f;
#pragma unroll
        for (int j = 0; j < 13; ++j) {
            const int ptj = 1 << j;
            up += interp_q(bits + ((size_t)b * SUM_PT + (ptj - 1)) * C_DIM + c, ptj, t);
        }
        const size_t idx = (size_t)pos * C_DIM + c;
        const float v = f[idx] - up;
        float bit;
        const float zh = bsq_eval(v, bit, pAcc, eAcc, cAcc);
        bits[((size_t)b * SUM_PT + (T_DIM - 1) + t) * C_DIM + c] = bit;
        outQ[idx] = up + zh;
    }
    write_partials(eAcc, cAcc, pAcc, partial, 13, blockIdx.x);
}

// ---------------------------------------------------------------------------
__global__ void reduce_partials(const float* __restrict__ partial, float* __restrict__ acc) {
    const int level = blockIdx.x / 34;
    const int comp = blockIdx.x % 34;
    const int nblk = (level < 8) ? 32 : PARTW;
    const float* s = partial + ((size_t)level * 34 + comp) * PARTW;
    float v = 0.f;
    for (int i = threadIdx.x; i < nblk; i += 64) v += s[i];
#pragma unroll
    for (int m = 32; m >= 1; m >>= 1) v += __shfl_xor(v, m, 64);
    if (threadIdx.x == 0) acc[level * 64 + comp] = v;
}

__global__ void finalize_kernel(const float* __restrict__ acc, float* __restrict__ outL) {
    const int k = threadIdx.x >> 5;
    const int c = threadIdx.x & 31;
    if (k >= NLEVEL) return;
    const float cnt = (float)(B_DIM << k);
    const float avg_p = acc[k * 64 + 2 + c] / cnt;
    float ec = entf(avg_p) + entf(1.0f - avg_p);
#pragma unroll
    for (int m = 16; m >= 1; m >>= 1) ec += __shfl_xor(ec, m, 32);
    if (c == 0) {
        const float per_sample = acc[k * 64 + 0] / cnt;
        const float commit = acc[k * 64 + 1] / cnt;
        const float pen = (per_sample - ec) * (1.0f / 100.0f);
        outL[k] = pen * 0.1f + commit * 0.2f;
    }
}

extern "C" void kernel_launch(void* const* d_in, const int* in_sizes, int n_in,
                              void* d_out, int out_size, void* d_ws, size_t ws_size,
                              hipStream_t stream) {
    (void)in_sizes; (void)n_in; (void)out_size; (void)ws_size;
    const float* f = (const float*)d_in[0];
    float* outQ = (float*)d_out;                        // N_ELEM floats
    float* outBits = outQ + N_ELEM;                     // BITS_ELEM floats (0.0/1.0)
    float* outL = outBits + BITS_ELEM;                  // 14 floats
    float* Racc = outQ;                                 // pool-4096 residual lives in outQ region

    float* partial = (float*)d_ws;                      // 14*34*2048 floats (~3.9MB)
    float* acc = partial + (size_t)NLEVEL * 34 * PARTW; // 14*64 floats
    float* F128 = acc + NLEVEL * 64;                    // B*128*C floats (0.5MB)

    initA_kernel<<<4096, 256, 0, stream>>>(f, Racc);
    initB_kernel<<<512, 256, 0, stream>>>(Racc, F128);
    fused_small_kernel<<<B_DIM, 256, 0, stream>>>(F128, outBits, partial);
    for (int k = 8; k < 13; ++k)
        level_kernel<<<2048, 256, 0, stream>>>(Racc, outBits, partial, k);
    final_kernel<<<2048, 256, 0, stream>>>(f, outQ, outBits, partial);
    reduce_partials<<<NLEVEL * 34, 64, 0, stream>>>(partial, acc);
    finalize_kernel<<<1, 512, 0, stream>>>(acc, outL);
}